// Round 6
// baseline (390.967 us; speedup 1.0000x reference)
//
#include <hip/hip_runtime.h>
#include <hip/hip_bf16.h>

#define LRELU_SLOPE 0.2f
#define BN_EPS 1e-5f

typedef __attribute__((ext_vector_type(8))) short short8v;
typedef __attribute__((ext_vector_type(4))) float float4v;

static __device__ __forceinline__ unsigned short f2bf(float f) {
    __hip_bfloat16 b = __float2bfloat16(f);
    return *reinterpret_cast<unsigned short*>(&b);
}
static __device__ __forceinline__ float bf2f(unsigned short u) {
    return __uint_as_float(((unsigned)u) << 16);
}
static __device__ __forceinline__ void unpack2(unsigned int u, float& f0, float& f1) {
    f0 = __uint_as_float(u << 16);
    f1 = __uint_as_float(u & 0xffff0000u);
}
static __device__ __forceinline__ float lrelu(float x) {
    return fmaxf(x, LRELU_SLOPE * x);
}

// ---------------- merged weight pre-convert: Wt[c][k] bf16 (both layers) ----------------
__global__ void convert_w2_kernel(const float* __restrict__ Wl0, const float* __restrict__ Wr0,
                                  const float* __restrict__ Wl1, const float* __restrict__ Wr1,
                                  unsigned short* __restrict__ Wt0, unsigned short* __restrict__ Wt1) {
    int idx = blockIdx.x * blockDim.x + threadIdx.x;
    if (idx < 384 * 128) {
        int c = idx >> 7, k = idx & 127;
        float v = (c < 192) ? Wl0[(size_t)k * 192 + c] : Wr0[(size_t)k * 192 + (c - 192)];
        Wt0[idx] = f2bf(v);
    } else if (idx < 384 * 128 + 128 * 192) {
        int i2 = idx - 384 * 128;
        int c = i2 / 192, k = i2 % 192;
        float v = (c < 64) ? Wl1[(size_t)k * 64 + c] : Wr1[(size_t)k * 64 + (c - 64)];
        Wt1[i2] = f2bf(v);
    }
}

// ---------------- CSR build (by dst) ----------------
__global__ void count_dst_kernel(const int* __restrict__ dst, int* __restrict__ counts, int E) {
    int e = blockIdx.x * blockDim.x + threadIdx.x;
    if (e < E) atomicAdd(&counts[dst[e]], 1);
}

__global__ void scanA_kernel(const int* __restrict__ counts, int* __restrict__ offs,
                             int* __restrict__ blkSum, int n) {
    __shared__ int wsum[4];
    const int lane = threadIdx.x & 63;
    const int wv = threadIdx.x >> 6;
    int i0 = blockIdx.x * 1024 + (int)threadIdx.x * 4;
    int v0 = (i0 + 0 < n) ? counts[i0 + 0] : 0;
    int v1 = (i0 + 1 < n) ? counts[i0 + 1] : 0;
    int v2 = (i0 + 2 < n) ? counts[i0 + 2] : 0;
    int v3 = (i0 + 3 < n) ? counts[i0 + 3] : 0;
    int s4 = v0 + v1 + v2 + v3;
    int s = s4;
    #pragma unroll
    for (int off = 1; off < 64; off <<= 1) {
        int t = __shfl_up(s, off, 64);
        if (lane >= off) s += t;
    }
    if (lane == 63) wsum[wv] = s;
    __syncthreads();
    int wpre = 0;
    for (int w = 0; w < wv; ++w) wpre += wsum[w];
    int excl = wpre + s - s4;
    if (i0 + 0 < n) offs[i0 + 0] = excl;
    excl += v0;
    if (i0 + 1 < n) offs[i0 + 1] = excl;
    excl += v1;
    if (i0 + 2 < n) offs[i0 + 2] = excl;
    excl += v2;
    if (i0 + 3 < n) offs[i0 + 3] = excl;
    if (threadIdx.x == 255) blkSum[blockIdx.x] = wpre + s;
}

__global__ void scanC_kernel(int* __restrict__ offs, const int* __restrict__ blkSum, int n, int E) {
    __shared__ int baseSh;
    const int b = blockIdx.x;
    if (threadIdx.x < 64) {
        int acc = 0;
        for (int i = threadIdx.x; i < b; i += 64) acc += blkSum[i];
        #pragma unroll
        for (int off = 1; off < 64; off <<= 1) acc += __shfl_xor(acc, off, 64);
        if (threadIdx.x == 0) baseSh = acc;
    }
    __syncthreads();
    const int base = baseSh;
    int i = b * 1024 + (int)threadIdx.x * 4;
    if (i + 3 < n) {
        int4 v = *reinterpret_cast<int4*>(&offs[i]);
        v.x += base; v.y += base; v.z += base; v.w += base;
        *reinterpret_cast<int4*>(&offs[i]) = v;
    } else {
        #pragma unroll
        for (int k = 0; k < 4; ++k)
            if (i + k < n) offs[i + k] += base;
    }
    if (b == 0 && threadIdx.x == 0) offs[n] = E;
}

__global__ void scatter_kernel(const int* __restrict__ src, const int* __restrict__ dst,
                               const int* __restrict__ offs, int* __restrict__ cursor,
                               int* __restrict__ esrc, int E) {
    int e = blockIdx.x * blockDim.x + threadIdx.x;
    if (e < E) {
        int d = dst[e];
        int pos = offs[d] + atomicAdd(&cursor[d], 1);
        esrc[pos] = src[e];
    }
}

// ---------------- MFMA dual GEMM (as round 5) ----------------
template <int K, int NCH, bool BN>
__global__ __launch_bounds__(256) void mfma_dual_gemm(
    const float* __restrict__ X,
    const unsigned short* __restrict__ Wt,
    const float* __restrict__ bl, const float* __restrict__ br,
    const float* __restrict__ stats, const float* __restrict__ gamma,
    const float* __restrict__ beta, float invN,
    unsigned short* __restrict__ out, int N) {
    constexpr int ST = 2 * NCH;
    constexpr int LDA = 40;
    const int rowBase = blockIdx.x * 128;
    const int colBase = blockIdx.y * 128;

    __shared__ unsigned short XS[128 * LDA];
    __shared__ unsigned short WS[128 * LDA];
    __shared__ float ssA[K], ssB[K];

    const int tid = threadIdx.x;
    const int lane = tid & 63;
    const int wv = tid >> 6;
    const int lrow = lane & 15;
    const int lk = lane >> 4;

    if (BN) {
        for (int c = tid; c < K; c += 256) {
            float mu = stats[c] * invN;
            float var = stats[K + c] * invN - mu * mu;
            float sc = gamma[c] * rsqrtf(var + BN_EPS);
            ssA[c] = sc;
            ssB[c] = beta[c] - mu * sc;
        }
        __syncthreads();
    }

    float4v acc[2][8];
    #pragma unroll
    for (int i = 0; i < 2; ++i)
        #pragma unroll
        for (int j = 0; j < 8; ++j) acc[i][j] = (float4v){0.f, 0.f, 0.f, 0.f};

    for (int k0 = 0; k0 < K; k0 += 32) {
        {
            int r = tid >> 3;
            int kq = (tid & 7) * 4;
            float4 sc0, sc1;
            if (BN) {
                sc0 = *reinterpret_cast<const float4*>(&ssA[k0 + kq]);
                sc1 = *reinterpret_cast<const float4*>(&ssB[k0 + kq]);
            }
            #pragma unroll
            for (int i = 0; i < 4; ++i) {
                int row = r + 32 * i;
                int gr = rowBase + row;
                float4 v = make_float4(0.f, 0.f, 0.f, 0.f);
                if (gr < N) v = *reinterpret_cast<const float4*>(&X[(size_t)gr * K + k0 + kq]);
                if (BN) {
                    v.x = v.x * sc0.x + sc1.x;
                    v.y = v.y * sc0.y + sc1.y;
                    v.z = v.z * sc0.z + sc1.z;
                    v.w = v.w * sc0.w + sc1.w;
                }
                ushort4 u;
                u.x = f2bf(v.x); u.y = f2bf(v.y); u.z = f2bf(v.z); u.w = f2bf(v.w);
                *reinterpret_cast<ushort4*>(&XS[row * LDA + kq]) = u;
            }
        }
        {
            int c = tid >> 2;
            int kq8 = (tid & 3) * 8;
            #pragma unroll
            for (int i = 0; i < 2; ++i) {
                int col = c + 64 * i;
                uint4 w = *reinterpret_cast<const uint4*>(&Wt[(size_t)(colBase + col) * K + k0 + kq8]);
                *reinterpret_cast<uint4*>(&WS[col * LDA + kq8]) = w;
            }
        }
        __syncthreads();
        short8v aF[2], bF[8];
        #pragma unroll
        for (int rb = 0; rb < 2; ++rb)
            aF[rb] = *reinterpret_cast<const short8v*>(&XS[(wv * 32 + rb * 16 + lrow) * LDA + lk * 8]);
        #pragma unroll
        for (int cb = 0; cb < 8; ++cb)
            bF[cb] = *reinterpret_cast<const short8v*>(&WS[(cb * 16 + lrow) * LDA + lk * 8]);
        #pragma unroll
        for (int rb = 0; rb < 2; ++rb)
            #pragma unroll
            for (int cb = 0; cb < 8; ++cb)
                acc[rb][cb] = __builtin_amdgcn_mfma_f32_16x16x32_bf16(aF[rb], bF[cb], acc[rb][cb], 0, 0, 0);
        __syncthreads();
    }
    #pragma unroll
    for (int cb = 0; cb < 8; ++cb) {
        int cg = colBase + cb * 16 + lrow;
        float bv = (cg < NCH) ? bl[cg] : br[cg - NCH];
        #pragma unroll
        for (int rb = 0; rb < 2; ++rb) {
            #pragma unroll
            for (int r = 0; r < 4; ++r) {
                int row = rowBase + wv * 32 + rb * 16 + lk * 4 + r;
                if (row < N) out[(size_t)row * ST + cg] = f2bf(acc[rb][cb][r] + bv);
            }
        }
    }
}

// ---------------- GATv2 agg H=3 + fused BN stats ----------------
// grid-stride over node groups (4 nodes/block); 4 edge slots x 16 lanes x 4ch;
// depth-2 prefetch; lrelu = max(x, 0.2x); per-block LDS stat accum, one flush.
__global__ __launch_bounds__(256) void gat_agg3_bn_kernel(
    const unsigned short* __restrict__ proj,  // [N, 384] bf16 [xl|xr]
    const int* __restrict__ offs, const int* __restrict__ esrc,
    const float* __restrict__ att, const float* __restrict__ bias,
    float* __restrict__ outh, float* __restrict__ stats,
    int N, int nGroups) {
    constexpr int H = 3, C = 64, HC = 192, ST = 384;
    __shared__ float ldsStats[2 * HC];
    const int tid = threadIdx.x;
    const int lane = tid & 63;
    const int wv = tid >> 6;
    const int j = lane >> 4;
    const int cg = (lane & 15) * 4;

    for (int i = tid; i < 2 * HC; i += 256) ldsStats[i] = 0.f;
    __syncthreads();

    float4 att4[H];
    #pragma unroll
    for (int h = 0; h < H; ++h) att4[h] = *reinterpret_cast<const float4*>(&att[h * C + cg]);

    for (int g = blockIdx.x; g < nGroups; g += gridDim.x) {
        const int node = g * 4 + wv;
        if (node >= N) continue;
        float4 xr4[H], acc4[H];
        float den[H];
        #pragma unroll
        for (int h = 0; h < H; ++h) {
            ushort4 u = *reinterpret_cast<const ushort4*>(&proj[(size_t)node * ST + HC + h * C + cg]);
            xr4[h] = make_float4(bf2f(u.x), bf2f(u.y), bf2f(u.z), bf2f(u.w));
            acc4[h] = make_float4(0.f, 0.f, 0.f, 0.f);
            den[h] = 0.f;
        }
        const int beg = offs[node];
        const int total = offs[node + 1] - beg + 1;  // virtual idx 0 = self loop
        ushort4 u0[H], u1[H];
        {
            int vc = (j < total) ? j : (total - 1);
            int s0 = (vc == 0) ? node : esrc[beg + vc - 1];
            #pragma unroll
            for (int h = 0; h < H; ++h)
                u0[h] = *reinterpret_cast<const ushort4*>(&proj[(size_t)s0 * ST + h * C + cg]);
            int v1i = j + 4;
            int vc1 = (v1i < total) ? v1i : (total - 1);
            int s1 = (vc1 == 0) ? node : esrc[beg + vc1 - 1];
            #pragma unroll
            for (int h = 0; h < H; ++h)
                u1[h] = *reinterpret_cast<const ushort4*>(&proj[(size_t)s1 * ST + h * C + cg]);
        }
        for (int t = 0; t < total; t += 4) {
            float4 xl4[H];
            #pragma unroll
            for (int h = 0; h < H; ++h) {
                xl4[h] = make_float4(bf2f(u0[h].x), bf2f(u0[h].y), bf2f(u0[h].z), bf2f(u0[h].w));
                u0[h] = u1[h];
            }
            const int v2 = t + 8 + j;
            if (v2 < total) {  // v2 >= 8 > 0: never self-loop
                int s2 = esrc[beg + v2 - 1];
                #pragma unroll
                for (int h = 0; h < H; ++h)
                    u1[h] = *reinterpret_cast<const ushort4*>(&proj[(size_t)s2 * ST + h * C + cg]);
            }
            float s[H];
            #pragma unroll
            for (int h = 0; h < H; ++h) {
                float a0 = lrelu(xl4[h].x + xr4[h].x);
                float a1 = lrelu(xl4[h].y + xr4[h].y);
                float a2 = lrelu(xl4[h].z + xr4[h].z);
                float a3 = lrelu(xl4[h].w + xr4[h].w);
                s[h] = a0 * att4[h].x + a1 * att4[h].y + a2 * att4[h].z + a3 * att4[h].w;
            }
            #pragma unroll
            for (int off = 1; off <= 8; off <<= 1)
                #pragma unroll
                for (int h = 0; h < H; ++h) s[h] += __shfl_xor(s[h], off, 64);
            const float w = (t + j < total) ? 1.f : 0.f;
            #pragma unroll
            for (int h = 0; h < H; ++h) {
                float p = w * __expf(s[h]);
                den[h] += p;
                acc4[h].x += p * xl4[h].x;
                acc4[h].y += p * xl4[h].y;
                acc4[h].z += p * xl4[h].z;
                acc4[h].w += p * xl4[h].w;
            }
        }
        #pragma unroll
        for (int off = 16; off <= 32; off <<= 1) {
            #pragma unroll
            for (int h = 0; h < H; ++h) {
                acc4[h].x += __shfl_xor(acc4[h].x, off, 64);
                acc4[h].y += __shfl_xor(acc4[h].y, off, 64);
                acc4[h].z += __shfl_xor(acc4[h].z, off, 64);
                acc4[h].w += __shfl_xor(acc4[h].w, off, 64);
                den[h]    += __shfl_xor(den[h],    off, 64);
            }
        }
        if (j == 0) {
            #pragma unroll
            for (int h = 0; h < H; ++h) {
                float4 b4 = *reinterpret_cast<const float4*>(&bias[h * C + cg]);
                float inv = 1.f / den[h];
                float4 o;
                o.x = fmaxf(acc4[h].x * inv + b4.x, 0.f);
                o.y = fmaxf(acc4[h].y * inv + b4.y, 0.f);
                o.z = fmaxf(acc4[h].z * inv + b4.z, 0.f);
                o.w = fmaxf(acc4[h].w * inv + b4.w, 0.f);
                *reinterpret_cast<float4*>(&outh[(size_t)node * HC + h * C + cg]) = o;
                atomicAdd(&ldsStats[h * C + cg + 0], o.x);
                atomicAdd(&ldsStats[h * C + cg + 1], o.y);
                atomicAdd(&ldsStats[h * C + cg + 2], o.z);
                atomicAdd(&ldsStats[h * C + cg + 3], o.w);
                atomicAdd(&ldsStats[HC + h * C + cg + 0], o.x * o.x);
                atomicAdd(&ldsStats[HC + h * C + cg + 1], o.y * o.y);
                atomicAdd(&ldsStats[HC + h * C + cg + 2], o.z * o.z);
                atomicAdd(&ldsStats[HC + h * C + cg + 3], o.w * o.w);
            }
        }
    }
    __syncthreads();
    for (int i = tid; i < 2 * HC; i += 256) atomicAdd(&stats[i], ldsStats[i]);
}

// ---------------- GATv2 agg H=1 + fused BN stats: 8 slots x 8 lanes x 8ch ----------------
__global__ __launch_bounds__(256) void gat_agg1_bn_kernel(
    const unsigned short* __restrict__ proj,  // [N,128] bf16 [xl|xr]
    const int* __restrict__ offs, const int* __restrict__ esrc,
    const float* __restrict__ att, const float* __restrict__ bias,
    float* __restrict__ outh, float* __restrict__ stats,
    int N, int nGroups) {
    __shared__ float ldsStats[128];
    const int tid = threadIdx.x;
    const int lane = tid & 63;
    const int wv = tid >> 6;
    const int j = lane >> 3;
    const int cg = (lane & 7) * 8;

    for (int i = tid; i < 128; i += 256) ldsStats[i] = 0.f;
    __syncthreads();

    float at[8];
    {
        float4 a0 = *reinterpret_cast<const float4*>(&att[cg]);
        float4 a1 = *reinterpret_cast<const float4*>(&att[cg + 4]);
        at[0] = a0.x; at[1] = a0.y; at[2] = a0.z; at[3] = a0.w;
        at[4] = a1.x; at[5] = a1.y; at[6] = a1.z; at[7] = a1.w;
    }

    for (int g = blockIdx.x; g < nGroups; g += gridDim.x) {
        const int node = g * 4 + wv;
        if (node >= N) continue;
        float xr[8], acc[8];
        float den = 0.f;
        {
            uint4 u = *reinterpret_cast<const uint4*>(&proj[(size_t)node * 128 + 64 + cg]);
            unpack2(u.x, xr[0], xr[1]); unpack2(u.y, xr[2], xr[3]);
            unpack2(u.z, xr[4], xr[5]); unpack2(u.w, xr[6], xr[7]);
            #pragma unroll
            for (int c = 0; c < 8; ++c) acc[c] = 0.f;
        }
        const int beg = offs[node];
        const int total = offs[node + 1] - beg + 1;
        uint4 u0, u1;
        {
            int vc = (j < total) ? j : (total - 1);
            int s0 = (vc == 0) ? node : esrc[beg + vc - 1];
            u0 = *reinterpret_cast<const uint4*>(&proj[(size_t)s0 * 128 + cg]);
            int v1i = j + 8;
            int vc1 = (v1i < total) ? v1i : (total - 1);
            int s1 = (vc1 == 0) ? node : esrc[beg + vc1 - 1];
            u1 = *reinterpret_cast<const uint4*>(&proj[(size_t)s1 * 128 + cg]);
        }
        for (int t = 0; t < total; t += 8) {
            float xl[8];
            unpack2(u0.x, xl[0], xl[1]); unpack2(u0.y, xl[2], xl[3]);
            unpack2(u0.z, xl[4], xl[5]); unpack2(u0.w, xl[6], xl[7]);
            u0 = u1;
            const int v2 = t + 16 + j;
            if (v2 < total) {
                int s2 = esrc[beg + v2 - 1];
                u1 = *reinterpret_cast<const uint4*>(&proj[(size_t)s2 * 128 + cg]);
            }
            float s = 0.f;
            #pragma unroll
            for (int c = 0; c < 8; ++c) s += lrelu(xl[c] + xr[c]) * at[c];
            #pragma unroll
            for (int off = 1; off <= 4; off <<= 1) s += __shfl_xor(s, off, 64);
            const float w = (t + j < total) ? 1.f : 0.f;
            float p = w * __expf(s);
            den += p;
            #pragma unroll
            for (int c = 0; c < 8; ++c) acc[c] += p * xl[c];
        }
        #pragma unroll
        for (int off = 8; off <= 32; off <<= 1) {
            den += __shfl_xor(den, off, 64);
            #pragma unroll
            for (int c = 0; c < 8; ++c) acc[c] += __shfl_xor(acc[c], off, 64);
        }
        if (j == 0) {
            float inv = 1.f / den;
            float4 b0 = *reinterpret_cast<const float4*>(&bias[cg]);
            float4 b1 = *reinterpret_cast<const float4*>(&bias[cg + 4]);
            float o[8];
            o[0] = fmaxf(acc[0] * inv + b0.x, 0.f); o[1] = fmaxf(acc[1] * inv + b0.y, 0.f);
            o[2] = fmaxf(acc[2] * inv + b0.z, 0.f); o[3] = fmaxf(acc[3] * inv + b0.w, 0.f);
            o[4] = fmaxf(acc[4] * inv + b1.x, 0.f); o[5] = fmaxf(acc[5] * inv + b1.y, 0.f);
            o[6] = fmaxf(acc[6] * inv + b1.z, 0.f); o[7] = fmaxf(acc[7] * inv + b1.w, 0.f);
            float4 w0 = make_float4(o[0], o[1], o[2], o[3]);
            float4 w1 = make_float4(o[4], o[5], o[6], o[7]);
            *reinterpret_cast<float4*>(&outh[(size_t)node * 64 + cg]) = w0;
            *reinterpret_cast<float4*>(&outh[(size_t)node * 64 + cg + 4]) = w1;
            #pragma unroll
            for (int c = 0; c < 8; ++c) {
                atomicAdd(&ldsStats[cg + c], o[c]);
                atomicAdd(&ldsStats[64 + cg + c], o[c] * o[c]);
            }
        }
    }
    __syncthreads();
    for (int i = tid; i < 128; i += 256) atomicAdd(&stats[i], ldsStats[i]);
}

// fused finalize+apply for CH=64
__global__ void bn_finapply64_kernel(float* __restrict__ h, const float* __restrict__ stats,
                                     const float* __restrict__ gamma, const float* __restrict__ beta,
                                     float invN, size_t total4) {
    size_t i = (size_t)blockIdx.x * blockDim.x + threadIdx.x;
    if (i >= total4) return;
    size_t e = i * 4;
    int c = (int)(e & 63);
    float4 v = *reinterpret_cast<float4*>(&h[e]);
    #pragma unroll
    for (int k = 0; k < 4; ++k) {
        float mu = stats[c + k] * invN;
        float var = stats[64 + c + k] * invN - mu * mu;
        float sc = gamma[c + k] * rsqrtf(var + BN_EPS);
        (&v.x)[k] = ((&v.x)[k] - mu) * sc + beta[c + k];
    }
    *reinterpret_cast<float4*>(&h[e]) = v;
}

extern "C" void kernel_launch(void* const* d_in, const int* in_sizes, int n_in,
                              void* d_out, int out_size, void* d_ws, size_t ws_size,
                              hipStream_t stream) {
    const float* x     = (const float*)d_in[0];
    const int*   eidx  = (const int*)d_in[1];
    const float* Wl0   = (const float*)d_in[2];
    const float* bl0   = (const float*)d_in[3];
    const float* Wr0   = (const float*)d_in[4];
    const float* br0   = (const float*)d_in[5];
    const float* att0  = (const float*)d_in[6];
    const float* bias0 = (const float*)d_in[7];
    const float* g0    = (const float*)d_in[8];
    const float* be0   = (const float*)d_in[9];
    const float* Wl1   = (const float*)d_in[10];
    const float* bl1   = (const float*)d_in[11];
    const float* Wr1   = (const float*)d_in[12];
    const float* br1   = (const float*)d_in[13];
    const float* att1  = (const float*)d_in[14];
    const float* bias1 = (const float*)d_in[15];
    const float* g1    = (const float*)d_in[16];
    const float* be1   = (const float*)d_in[17];

    const int N = in_sizes[0] / 128;
    const int E = in_sizes[1] / 2;
    const int* srcIdx = eidx;
    const int* dstIdx = eidx + E;
    const int nChunks = (N + 1023) >> 10;
    const int nGroups = (N + 3) / 4;
    const float invN = 1.f / (float)N;

    char* base = (char*)d_ws;
    auto alloc = [&](size_t bytes) {
        char* p = base;
        base += (bytes + 255) & ~(size_t)255;
        return p;
    };
    unsigned short* proj = (unsigned short*)alloc((size_t)N * 384 * 2);
    float* h0    = (float*)alloc((size_t)N * 192 * 4);
    int*   offs  = (int*)alloc((size_t)(N + 1) * 4);
    int*   esrc  = (int*)alloc((size_t)E * 4);
    int*   blkSum= (int*)alloc((size_t)nChunks * 4);
    unsigned short* Wt0 = (unsigned short*)alloc((size_t)384 * 128 * 2);
    unsigned short* Wt1 = (unsigned short*)alloc((size_t)128 * 192 * 2);
    // contiguous zero region: counts | cursor | stats0 | stats1
    char* zeroBeg = base;
    int*   counts = (int*)alloc((size_t)N * 4);
    int*   cursor = (int*)alloc((size_t)N * 4);
    float* stats0 = (float*)alloc(384 * 4);
    float* stats1 = (float*)alloc(128 * 4);
    size_t zeroBytes = (size_t)(base - zeroBeg);

    hipMemsetAsync(zeroBeg, 0, zeroBytes, stream);
    convert_w2_kernel<<<(384 * 128 + 128 * 192 + 255) / 256, 256, 0, stream>>>(Wl0, Wr0, Wl1, Wr1, Wt0, Wt1);

    // ---- CSR by dst ----
    count_dst_kernel<<<(E + 255) / 256, 256, 0, stream>>>(dstIdx, counts, E);
    scanA_kernel<<<nChunks, 256, 0, stream>>>(counts, offs, blkSum, N);
    scanC_kernel<<<nChunks, 256, 0, stream>>>(offs, blkSum, N, E);
    scatter_kernel<<<(E + 255) / 256, 256, 0, stream>>>(srcIdx, dstIdx, offs, cursor, esrc, E);

    // ---- layer 0: 128 -> 3x64 (concat 192) ----
    {
        dim3 grid((N + 127) / 128, 3);
        mfma_dual_gemm<128, 192, false><<<grid, 256, 0, stream>>>(
            x, Wt0, bl0, br0, nullptr, nullptr, nullptr, 0.f, proj, N);
    }
    {
        int blocks = nGroups < 1536 ? nGroups : 1536;
        gat_agg3_bn_kernel<<<blocks, 256, 0, stream>>>(proj, offs, esrc, att0, bias0, h0, stats0, N, nGroups);
    }

    // ---- layer 1: 192 -> 1x64 (BN finalize+apply fused into A staging) ----
    {
        dim3 grid((N + 127) / 128, 1);
        mfma_dual_gemm<192, 64, true><<<grid, 256, 0, stream>>>(
            h0, Wt1, bl1, br1, stats0, g0, be0, invN, proj, N);
    }
    float* out = (float*)d_out;
    {
        int blocks = nGroups < 1536 ? nGroups : 1536;
        gat_agg1_bn_kernel<<<blocks, 256, 0, stream>>>(proj, offs, esrc, att1, bias1, out, stats1, N, nGroups);
    }
    {
        size_t tot4 = (size_t)N * 16;
        bn_finapply64_kernel<<<(unsigned)((tot4 + 255) / 256), 256, 0, stream>>>(out, stats1, g1, be1, invN, tot4);
    }
}

// Round 7
// 342.195 us; speedup vs baseline: 1.1425x; 1.1425x over previous
//
#include <hip/hip_runtime.h>
#include <hip/hip_bf16.h>

#define LRELU_SLOPE 0.2f
#define BN_EPS 1e-5f

typedef __attribute__((ext_vector_type(8))) short short8v;
typedef __attribute__((ext_vector_type(4))) float float4v;

static __device__ __forceinline__ unsigned short f2bf(float f) {
    __hip_bfloat16 b = __float2bfloat16(f);
    return *reinterpret_cast<unsigned short*>(&b);
}
static __device__ __forceinline__ float bf2f(unsigned short u) {
    return __uint_as_float(((unsigned)u) << 16);
}
static __device__ __forceinline__ void unpack2(unsigned int u, float& f0, float& f1) {
    f0 = __uint_as_float(u << 16);
    f1 = __uint_as_float(u & 0xffff0000u);
}
static __device__ __forceinline__ float lrelu(float x) {
    return fmaxf(x, LRELU_SLOPE * x);
}

// ---------------- merged weight pre-convert: Wt[c][k] bf16 (both layers) ----------------
__global__ void convert_w2_kernel(const float* __restrict__ Wl0, const float* __restrict__ Wr0,
                                  const float* __restrict__ Wl1, const float* __restrict__ Wr1,
                                  unsigned short* __restrict__ Wt0, unsigned short* __restrict__ Wt1) {
    int idx = blockIdx.x * blockDim.x + threadIdx.x;
    if (idx < 384 * 128) {
        int c = idx >> 7, k = idx & 127;
        float v = (c < 192) ? Wl0[(size_t)k * 192 + c] : Wr0[(size_t)k * 192 + (c - 192)];
        Wt0[idx] = f2bf(v);
    } else if (idx < 384 * 128 + 128 * 192) {
        int i2 = idx - 384 * 128;
        int c = i2 / 192, k = i2 % 192;
        float v = (c < 64) ? Wl1[(size_t)k * 64 + c] : Wr1[(size_t)k * 64 + (c - 64)];
        Wt1[i2] = f2bf(v);
    }
}

// ---------------- CSR build (by dst) ----------------
__global__ void count_dst_kernel(const int* __restrict__ dst, int* __restrict__ counts, int E) {
    int e = blockIdx.x * blockDim.x + threadIdx.x;
    if (e < E) atomicAdd(&counts[dst[e]], 1);
}

__global__ void scanA_kernel(const int* __restrict__ counts, int* __restrict__ offs,
                             int* __restrict__ blkSum, int n) {
    __shared__ int wsum[4];
    const int lane = threadIdx.x & 63;
    const int wv = threadIdx.x >> 6;
    int i0 = blockIdx.x * 1024 + (int)threadIdx.x * 4;
    int v0 = (i0 + 0 < n) ? counts[i0 + 0] : 0;
    int v1 = (i0 + 1 < n) ? counts[i0 + 1] : 0;
    int v2 = (i0 + 2 < n) ? counts[i0 + 2] : 0;
    int v3 = (i0 + 3 < n) ? counts[i0 + 3] : 0;
    int s4 = v0 + v1 + v2 + v3;
    int s = s4;
    #pragma unroll
    for (int off = 1; off < 64; off <<= 1) {
        int t = __shfl_up(s, off, 64);
        if (lane >= off) s += t;
    }
    if (lane == 63) wsum[wv] = s;
    __syncthreads();
    int wpre = 0;
    for (int w = 0; w < wv; ++w) wpre += wsum[w];
    int excl = wpre + s - s4;
    if (i0 + 0 < n) offs[i0 + 0] = excl;
    excl += v0;
    if (i0 + 1 < n) offs[i0 + 1] = excl;
    excl += v1;
    if (i0 + 2 < n) offs[i0 + 2] = excl;
    excl += v2;
    if (i0 + 3 < n) offs[i0 + 3] = excl;
    if (threadIdx.x == 255) blkSum[blockIdx.x] = wpre + s;
}

__global__ void scanC_kernel(int* __restrict__ offs, const int* __restrict__ blkSum, int n, int E) {
    __shared__ int baseSh;
    const int b = blockIdx.x;
    if (threadIdx.x < 64) {
        int acc = 0;
        for (int i = threadIdx.x; i < b; i += 64) acc += blkSum[i];
        #pragma unroll
        for (int off = 1; off < 64; off <<= 1) acc += __shfl_xor(acc, off, 64);
        if (threadIdx.x == 0) baseSh = acc;
    }
    __syncthreads();
    const int base = baseSh;
    int i = b * 1024 + (int)threadIdx.x * 4;
    if (i + 3 < n) {
        int4 v = *reinterpret_cast<int4*>(&offs[i]);
        v.x += base; v.y += base; v.z += base; v.w += base;
        *reinterpret_cast<int4*>(&offs[i]) = v;
    } else {
        #pragma unroll
        for (int k = 0; k < 4; ++k)
            if (i + k < n) offs[i + k] += base;
    }
    if (b == 0 && threadIdx.x == 0) offs[n] = E;
}

__global__ void scatter_kernel(const int* __restrict__ src, const int* __restrict__ dst,
                               const int* __restrict__ offs, int* __restrict__ cursor,
                               int* __restrict__ esrc, int E) {
    int e = blockIdx.x * blockDim.x + threadIdx.x;
    if (e < E) {
        int d = dst[e];
        int pos = offs[d] + atomicAdd(&cursor[d], 1);
        esrc[pos] = src[e];
    }
}

// ---------------- MFMA dual GEMM ----------------
template <int K, int NCH, bool BN>
__global__ __launch_bounds__(256) void mfma_dual_gemm(
    const float* __restrict__ X,
    const unsigned short* __restrict__ Wt,
    const float* __restrict__ bl, const float* __restrict__ br,
    const float* __restrict__ stats, const float* __restrict__ gamma,
    const float* __restrict__ beta, float invN,
    unsigned short* __restrict__ out, int N) {
    constexpr int ST = 2 * NCH;
    constexpr int LDA = 40;
    const int rowBase = blockIdx.x * 128;
    const int colBase = blockIdx.y * 128;

    __shared__ unsigned short XS[128 * LDA];
    __shared__ unsigned short WS[128 * LDA];
    __shared__ float ssA[K], ssB[K];

    const int tid = threadIdx.x;
    const int lane = tid & 63;
    const int wv = tid >> 6;
    const int lrow = lane & 15;
    const int lk = lane >> 4;

    if (BN) {
        for (int c = tid; c < K; c += 256) {
            float mu = stats[c] * invN;
            float var = stats[K + c] * invN - mu * mu;
            float sc = gamma[c] * rsqrtf(var + BN_EPS);
            ssA[c] = sc;
            ssB[c] = beta[c] - mu * sc;
        }
        __syncthreads();
    }

    float4v acc[2][8];
    #pragma unroll
    for (int i = 0; i < 2; ++i)
        #pragma unroll
        for (int j = 0; j < 8; ++j) acc[i][j] = (float4v){0.f, 0.f, 0.f, 0.f};

    for (int k0 = 0; k0 < K; k0 += 32) {
        {
            int r = tid >> 3;
            int kq = (tid & 7) * 4;
            float4 sc0, sc1;
            if (BN) {
                sc0 = *reinterpret_cast<const float4*>(&ssA[k0 + kq]);
                sc1 = *reinterpret_cast<const float4*>(&ssB[k0 + kq]);
            }
            #pragma unroll
            for (int i = 0; i < 4; ++i) {
                int row = r + 32 * i;
                int gr = rowBase + row;
                float4 v = make_float4(0.f, 0.f, 0.f, 0.f);
                if (gr < N) v = *reinterpret_cast<const float4*>(&X[(size_t)gr * K + k0 + kq]);
                if (BN) {
                    v.x = v.x * sc0.x + sc1.x;
                    v.y = v.y * sc0.y + sc1.y;
                    v.z = v.z * sc0.z + sc1.z;
                    v.w = v.w * sc0.w + sc1.w;
                }
                ushort4 u;
                u.x = f2bf(v.x); u.y = f2bf(v.y); u.z = f2bf(v.z); u.w = f2bf(v.w);
                *reinterpret_cast<ushort4*>(&XS[row * LDA + kq]) = u;
            }
        }
        {
            int c = tid >> 2;
            int kq8 = (tid & 3) * 8;
            #pragma unroll
            for (int i = 0; i < 2; ++i) {
                int col = c + 64 * i;
                uint4 w = *reinterpret_cast<const uint4*>(&Wt[(size_t)(colBase + col) * K + k0 + kq8]);
                *reinterpret_cast<uint4*>(&WS[col * LDA + kq8]) = w;
            }
        }
        __syncthreads();
        short8v aF[2], bF[8];
        #pragma unroll
        for (int rb = 0; rb < 2; ++rb)
            aF[rb] = *reinterpret_cast<const short8v*>(&XS[(wv * 32 + rb * 16 + lrow) * LDA + lk * 8]);
        #pragma unroll
        for (int cb = 0; cb < 8; ++cb)
            bF[cb] = *reinterpret_cast<const short8v*>(&WS[(cb * 16 + lrow) * LDA + lk * 8]);
        #pragma unroll
        for (int rb = 0; rb < 2; ++rb)
            #pragma unroll
            for (int cb = 0; cb < 8; ++cb)
                acc[rb][cb] = __builtin_amdgcn_mfma_f32_16x16x32_bf16(aF[rb], bF[cb], acc[rb][cb], 0, 0, 0);
        __syncthreads();
    }
    #pragma unroll
    for (int cb = 0; cb < 8; ++cb) {
        int cg = colBase + cb * 16 + lrow;
        float bv = (cg < NCH) ? bl[cg] : br[cg - NCH];
        #pragma unroll
        for (int rb = 0; rb < 2; ++rb) {
            #pragma unroll
            for (int r = 0; r < 4; ++r) {
                int row = rowBase + wv * 32 + rb * 16 + lk * 4 + r;
                if (row < N) out[(size_t)row * ST + cg] = f2bf(acc[rb][cb][r] + bv);
            }
        }
    }
}

// ---------------- GATv2 agg H=3 + fused BN stats (register accumulation) ----------------
// grid-stride (persistent blocks); 4 edge slots x 16 lanes x 4ch; depth-2 prefetch.
// BN stats accumulate in j==0 lanes' REGISTERS across all groups; single LDS+global
// flush per block at kernel end (no per-group atomics — that was round 6's 2x regression).
__global__ __launch_bounds__(256) void gat_agg3_bn_kernel(
    const unsigned short* __restrict__ proj,  // [N, 384] bf16 [xl|xr]
    const int* __restrict__ offs, const int* __restrict__ esrc,
    const float* __restrict__ att, const float* __restrict__ bias,
    float* __restrict__ outh, float* __restrict__ stats,
    int N, int nGroups) {
    constexpr int H = 3, C = 64, HC = 192, ST = 384;
    __shared__ float ldsStats[2 * HC];
    const int tid = threadIdx.x;
    const int lane = tid & 63;
    const int wv = tid >> 6;
    const int j = lane >> 4;
    const int cg = (lane & 15) * 4;

    float4 att4[H];
    #pragma unroll
    for (int h = 0; h < H; ++h) att4[h] = *reinterpret_cast<const float4*>(&att[h * C + cg]);

    float sSum[H][4] = {};
    float sSq[H][4] = {};

    for (int g = blockIdx.x; g < nGroups; g += gridDim.x) {
        const int node = g * 4 + wv;
        if (node >= N) continue;
        float4 xr4[H], acc4[H];
        float den[H];
        #pragma unroll
        for (int h = 0; h < H; ++h) {
            ushort4 u = *reinterpret_cast<const ushort4*>(&proj[(size_t)node * ST + HC + h * C + cg]);
            xr4[h] = make_float4(bf2f(u.x), bf2f(u.y), bf2f(u.z), bf2f(u.w));
            acc4[h] = make_float4(0.f, 0.f, 0.f, 0.f);
            den[h] = 0.f;
        }
        const int beg = offs[node];
        const int total = offs[node + 1] - beg + 1;  // virtual idx 0 = self loop
        ushort4 u0[H], u1[H];
        {
            int vc = (j < total) ? j : (total - 1);
            int s0 = (vc == 0) ? node : esrc[beg + vc - 1];
            #pragma unroll
            for (int h = 0; h < H; ++h)
                u0[h] = *reinterpret_cast<const ushort4*>(&proj[(size_t)s0 * ST + h * C + cg]);
            int v1i = j + 4;
            int vc1 = (v1i < total) ? v1i : (total - 1);
            int s1 = (vc1 == 0) ? node : esrc[beg + vc1 - 1];
            #pragma unroll
            for (int h = 0; h < H; ++h)
                u1[h] = *reinterpret_cast<const ushort4*>(&proj[(size_t)s1 * ST + h * C + cg]);
        }
        for (int t = 0; t < total; t += 4) {
            float4 xl4[H];
            #pragma unroll
            for (int h = 0; h < H; ++h) {
                xl4[h] = make_float4(bf2f(u0[h].x), bf2f(u0[h].y), bf2f(u0[h].z), bf2f(u0[h].w));
                u0[h] = u1[h];
            }
            const int v2 = t + 8 + j;
            if (v2 < total) {  // v2 >= 8 > 0: never self-loop
                int s2 = esrc[beg + v2 - 1];
                #pragma unroll
                for (int h = 0; h < H; ++h)
                    u1[h] = *reinterpret_cast<const ushort4*>(&proj[(size_t)s2 * ST + h * C + cg]);
            }
            float s[H];
            #pragma unroll
            for (int h = 0; h < H; ++h) {
                float a0 = lrelu(xl4[h].x + xr4[h].x);
                float a1 = lrelu(xl4[h].y + xr4[h].y);
                float a2 = lrelu(xl4[h].z + xr4[h].z);
                float a3 = lrelu(xl4[h].w + xr4[h].w);
                s[h] = a0 * att4[h].x + a1 * att4[h].y + a2 * att4[h].z + a3 * att4[h].w;
            }
            #pragma unroll
            for (int off = 1; off <= 8; off <<= 1)
                #pragma unroll
                for (int h = 0; h < H; ++h) s[h] += __shfl_xor(s[h], off, 64);
            const float w = (t + j < total) ? 1.f : 0.f;
            #pragma unroll
            for (int h = 0; h < H; ++h) {
                float p = w * __expf(s[h]);
                den[h] += p;
                acc4[h].x += p * xl4[h].x;
                acc4[h].y += p * xl4[h].y;
                acc4[h].z += p * xl4[h].z;
                acc4[h].w += p * xl4[h].w;
            }
        }
        #pragma unroll
        for (int off = 16; off <= 32; off <<= 1) {
            #pragma unroll
            for (int h = 0; h < H; ++h) {
                acc4[h].x += __shfl_xor(acc4[h].x, off, 64);
                acc4[h].y += __shfl_xor(acc4[h].y, off, 64);
                acc4[h].z += __shfl_xor(acc4[h].z, off, 64);
                acc4[h].w += __shfl_xor(acc4[h].w, off, 64);
                den[h]    += __shfl_xor(den[h],    off, 64);
            }
        }
        if (j == 0) {
            #pragma unroll
            for (int h = 0; h < H; ++h) {
                float4 b4 = *reinterpret_cast<const float4*>(&bias[h * C + cg]);
                float inv = 1.f / den[h];
                float4 o;
                o.x = fmaxf(acc4[h].x * inv + b4.x, 0.f);
                o.y = fmaxf(acc4[h].y * inv + b4.y, 0.f);
                o.z = fmaxf(acc4[h].z * inv + b4.z, 0.f);
                o.w = fmaxf(acc4[h].w * inv + b4.w, 0.f);
                *reinterpret_cast<float4*>(&outh[(size_t)node * HC + h * C + cg]) = o;
                sSum[h][0] += o.x; sSum[h][1] += o.y; sSum[h][2] += o.z; sSum[h][3] += o.w;
                sSq[h][0] += o.x * o.x; sSq[h][1] += o.y * o.y;
                sSq[h][2] += o.z * o.z; sSq[h][3] += o.w * o.w;
            }
        }
    }
    // block-level flush (once)
    for (int i = tid; i < 2 * HC; i += 256) ldsStats[i] = 0.f;
    __syncthreads();
    if (j == 0) {
        #pragma unroll
        for (int h = 0; h < H; ++h)
            #pragma unroll
            for (int k = 0; k < 4; ++k) {
                atomicAdd(&ldsStats[h * C + cg + k], sSum[h][k]);
                atomicAdd(&ldsStats[HC + h * C + cg + k], sSq[h][k]);
            }
    }
    __syncthreads();
    for (int i = tid; i < 2 * HC; i += 256) atomicAdd(&stats[i], ldsStats[i]);
}

// ---------------- GATv2 agg H=1 + fused BN stats: 8 slots x 8 lanes x 8ch ----------------
__global__ __launch_bounds__(256) void gat_agg1_bn_kernel(
    const unsigned short* __restrict__ proj,  // [N,128] bf16 [xl|xr]
    const int* __restrict__ offs, const int* __restrict__ esrc,
    const float* __restrict__ att, const float* __restrict__ bias,
    float* __restrict__ outh, float* __restrict__ stats,
    int N, int nGroups) {
    __shared__ float ldsStats[128];
    const int tid = threadIdx.x;
    const int lane = tid & 63;
    const int wv = tid >> 6;
    const int j = lane >> 3;
    const int cg = (lane & 7) * 8;

    float at[8];
    {
        float4 a0 = *reinterpret_cast<const float4*>(&att[cg]);
        float4 a1 = *reinterpret_cast<const float4*>(&att[cg + 4]);
        at[0] = a0.x; at[1] = a0.y; at[2] = a0.z; at[3] = a0.w;
        at[4] = a1.x; at[5] = a1.y; at[6] = a1.z; at[7] = a1.w;
    }
    float sSum[8] = {};
    float sSq[8] = {};

    for (int g = blockIdx.x; g < nGroups; g += gridDim.x) {
        const int node = g * 4 + wv;
        if (node >= N) continue;
        float xr[8], acc[8];
        float den = 0.f;
        {
            uint4 u = *reinterpret_cast<const uint4*>(&proj[(size_t)node * 128 + 64 + cg]);
            unpack2(u.x, xr[0], xr[1]); unpack2(u.y, xr[2], xr[3]);
            unpack2(u.z, xr[4], xr[5]); unpack2(u.w, xr[6], xr[7]);
            #pragma unroll
            for (int c = 0; c < 8; ++c) acc[c] = 0.f;
        }
        const int beg = offs[node];
        const int total = offs[node + 1] - beg + 1;
        uint4 u0, u1;
        {
            int vc = (j < total) ? j : (total - 1);
            int s0 = (vc == 0) ? node : esrc[beg + vc - 1];
            u0 = *reinterpret_cast<const uint4*>(&proj[(size_t)s0 * 128 + cg]);
            int v1i = j + 8;
            int vc1 = (v1i < total) ? v1i : (total - 1);
            int s1 = (vc1 == 0) ? node : esrc[beg + vc1 - 1];
            u1 = *reinterpret_cast<const uint4*>(&proj[(size_t)s1 * 128 + cg]);
        }
        for (int t = 0; t < total; t += 8) {
            float xl[8];
            unpack2(u0.x, xl[0], xl[1]); unpack2(u0.y, xl[2], xl[3]);
            unpack2(u0.z, xl[4], xl[5]); unpack2(u0.w, xl[6], xl[7]);
            u0 = u1;
            const int v2 = t + 16 + j;
            if (v2 < total) {
                int s2 = esrc[beg + v2 - 1];
                u1 = *reinterpret_cast<const uint4*>(&proj[(size_t)s2 * 128 + cg]);
            }
            float s = 0.f;
            #pragma unroll
            for (int c = 0; c < 8; ++c) s += lrelu(xl[c] + xr[c]) * at[c];
            #pragma unroll
            for (int off = 1; off <= 4; off <<= 1) s += __shfl_xor(s, off, 64);
            const float w = (t + j < total) ? 1.f : 0.f;
            float p = w * __expf(s);
            den += p;
            #pragma unroll
            for (int c = 0; c < 8; ++c) acc[c] += p * xl[c];
        }
        #pragma unroll
        for (int off = 8; off <= 32; off <<= 1) {
            den += __shfl_xor(den, off, 64);
            #pragma unroll
            for (int c = 0; c < 8; ++c) acc[c] += __shfl_xor(acc[c], off, 64);
        }
        if (j == 0) {
            float inv = 1.f / den;
            float4 b0 = *reinterpret_cast<const float4*>(&bias[cg]);
            float4 b1 = *reinterpret_cast<const float4*>(&bias[cg + 4]);
            float o[8];
            o[0] = fmaxf(acc[0] * inv + b0.x, 0.f); o[1] = fmaxf(acc[1] * inv + b0.y, 0.f);
            o[2] = fmaxf(acc[2] * inv + b0.z, 0.f); o[3] = fmaxf(acc[3] * inv + b0.w, 0.f);
            o[4] = fmaxf(acc[4] * inv + b1.x, 0.f); o[5] = fmaxf(acc[5] * inv + b1.y, 0.f);
            o[6] = fmaxf(acc[6] * inv + b1.z, 0.f); o[7] = fmaxf(acc[7] * inv + b1.w, 0.f);
            *reinterpret_cast<float4*>(&outh[(size_t)node * 64 + cg]) = make_float4(o[0], o[1], o[2], o[3]);
            *reinterpret_cast<float4*>(&outh[(size_t)node * 64 + cg + 4]) = make_float4(o[4], o[5], o[6], o[7]);
            #pragma unroll
            for (int c = 0; c < 8; ++c) {
                sSum[c] += o[c];
                sSq[c] += o[c] * o[c];
            }
        }
    }
    for (int i = tid; i < 128; i += 256) ldsStats[i] = 0.f;
    __syncthreads();
    if (j == 0) {
        #pragma unroll
        for (int c = 0; c < 8; ++c) {
            atomicAdd(&ldsStats[cg + c], sSum[c]);
            atomicAdd(&ldsStats[64 + cg + c], sSq[c]);
        }
    }
    __syncthreads();
    for (int i = tid; i < 128; i += 256) atomicAdd(&stats[i], ldsStats[i]);
}

// fused finalize+apply for CH=64
__global__ void bn_finapply64_kernel(float* __restrict__ h, const float* __restrict__ stats,
                                     const float* __restrict__ gamma, const float* __restrict__ beta,
                                     float invN, size_t total4) {
    size_t i = (size_t)blockIdx.x * blockDim.x + threadIdx.x;
    if (i >= total4) return;
    size_t e = i * 4;
    int c = (int)(e & 63);
    float4 v = *reinterpret_cast<float4*>(&h[e]);
    #pragma unroll
    for (int k = 0; k < 4; ++k) {
        float mu = stats[c + k] * invN;
        float var = stats[64 + c + k] * invN - mu * mu;
        float sc = gamma[c + k] * rsqrtf(var + BN_EPS);
        (&v.x)[k] = ((&v.x)[k] - mu) * sc + beta[c + k];
    }
    *reinterpret_cast<float4*>(&h[e]) = v;
}

extern "C" void kernel_launch(void* const* d_in, const int* in_sizes, int n_in,
                              void* d_out, int out_size, void* d_ws, size_t ws_size,
                              hipStream_t stream) {
    const float* x     = (const float*)d_in[0];
    const int*   eidx  = (const int*)d_in[1];
    const float* Wl0   = (const float*)d_in[2];
    const float* bl0   = (const float*)d_in[3];
    const float* Wr0   = (const float*)d_in[4];
    const float* br0   = (const float*)d_in[5];
    const float* att0  = (const float*)d_in[6];
    const float* bias0 = (const float*)d_in[7];
    const float* g0    = (const float*)d_in[8];
    const float* be0   = (const float*)d_in[9];
    const float* Wl1   = (const float*)d_in[10];
    const float* bl1   = (const float*)d_in[11];
    const float* Wr1   = (const float*)d_in[12];
    const float* br1   = (const float*)d_in[13];
    const float* att1  = (const float*)d_in[14];
    const float* bias1 = (const float*)d_in[15];
    const float* g1    = (const float*)d_in[16];
    const float* be1   = (const float*)d_in[17];

    const int N = in_sizes[0] / 128;
    const int E = in_sizes[1] / 2;
    const int* srcIdx = eidx;
    const int* dstIdx = eidx + E;
    const int nChunks = (N + 1023) >> 10;
    const int nGroups = (N + 3) / 4;
    const float invN = 1.f / (float)N;

    char* base = (char*)d_ws;
    auto alloc = [&](size_t bytes) {
        char* p = base;
        base += (bytes + 255) & ~(size_t)255;
        return p;
    };
    unsigned short* proj = (unsigned short*)alloc((size_t)N * 384 * 2);
    float* h0    = (float*)alloc((size_t)N * 192 * 4);
    int*   offs  = (int*)alloc((size_t)(N + 1) * 4);
    int*   esrc  = (int*)alloc((size_t)E * 4);
    int*   blkSum= (int*)alloc((size_t)nChunks * 4);
    unsigned short* Wt0 = (unsigned short*)alloc((size_t)384 * 128 * 2);
    unsigned short* Wt1 = (unsigned short*)alloc((size_t)128 * 192 * 2);
    // contiguous zero region: counts | cursor | stats0 | stats1
    char* zeroBeg = base;
    int*   counts = (int*)alloc((size_t)N * 4);
    int*   cursor = (int*)alloc((size_t)N * 4);
    float* stats0 = (float*)alloc(384 * 4);
    float* stats1 = (float*)alloc(128 * 4);
    size_t zeroBytes = (size_t)(base - zeroBeg);

    hipMemsetAsync(zeroBeg, 0, zeroBytes, stream);
    convert_w2_kernel<<<(384 * 128 + 128 * 192 + 255) / 256, 256, 0, stream>>>(Wl0, Wr0, Wl1, Wr1, Wt0, Wt1);

    // ---- CSR by dst ----
    count_dst_kernel<<<(E + 255) / 256, 256, 0, stream>>>(dstIdx, counts, E);
    scanA_kernel<<<nChunks, 256, 0, stream>>>(counts, offs, blkSum, N);
    scanC_kernel<<<nChunks, 256, 0, stream>>>(offs, blkSum, N, E);
    scatter_kernel<<<(E + 255) / 256, 256, 0, stream>>>(srcIdx, dstIdx, offs, cursor, esrc, E);

    // ---- layer 0: 128 -> 3x64 (concat 192) ----
    {
        dim3 grid((N + 127) / 128, 3);
        mfma_dual_gemm<128, 192, false><<<grid, 256, 0, stream>>>(
            x, Wt0, bl0, br0, nullptr, nullptr, nullptr, 0.f, proj, N);
    }
    {
        int blocks = nGroups < 2048 ? nGroups : 2048;
        gat_agg3_bn_kernel<<<blocks, 256, 0, stream>>>(proj, offs, esrc, att0, bias0, h0, stats0, N, nGroups);
    }

    // ---- layer 1: 192 -> 1x64 (BN finalize+apply fused into A staging) ----
    {
        dim3 grid((N + 127) / 128, 1);
        mfma_dual_gemm<192, 64, true><<<grid, 256, 0, stream>>>(
            h0, Wt1, bl1, br1, stats0, g0, be0, invN, proj, N);
    }
    float* out = (float*)d_out;
    {
        int blocks = nGroups < 2048 ? nGroups : 2048;
        gat_agg1_bn_kernel<<<blocks, 256, 0, stream>>>(proj, offs, esrc, att1, bias1, out, stats1, N, nGroups);
    }
    {
        size_t tot4 = (size_t)N * 16;
        bn_finapply64_kernel<<<(unsigned)((tot4 + 255) / 256), 256, 0, stream>>>(out, stats1, g1, be1, invN, tot4);
    }
}